// Round 3
// baseline (128.450 us; speedup 1.0000x reference)
//
#include <hip/hip_runtime.h>
#include <hip/hip_fp16.h>

// GCN-style symmetric-normalized CSR aggregation.
// out[d][f] = sum_e feat[col_idx[e]][f] * rsqrt(deg[d]*deg[col_idx[e]])
//
// Round-9 theory: latency-bound with MLP~2. r8 (persistent waves) was
// neutral -> residency was never the limiter; the inner loop issues 2
// gathers then immediately waits (vmcnt(0)) before unpacking, and the
// col_idx load serializes ahead. Fix:
//  1. Batch 8 independent 16B gathers (q[0..7]) before ANY consumption:
//     MLP 2 -> 8. Zero-row clamp makes full unroll branch-free.
//  2. Prefetch next pair's first col_idx block + row bounds + deg during
//     current pair's accumulate: steady-state critical path loses the
//     col_idx -> shfl -> gather serial hop.
//  3. launch_bounds(256,6): VGPR cap 85 (est ~70), no spills, 24 waves/CU.

typedef float    v4f __attribute__((ext_vector_type(4)));
typedef unsigned v4u __attribute__((ext_vector_type(4)));

// ---------------- pass 1: fold rsqrt(deg[src]) -> fp16 table (+ zero row) ---
__global__ __launch_bounds__(256) void conv_fold(
    const float4* __restrict__ in, const float* __restrict__ deg,
    uint2* __restrict__ out, int n4)
{
    const int i = blockIdx.x * blockDim.x + threadIdx.x;
    if (i >= n4 + 16) return;
    if (i >= n4) { out[i] = make_uint2(0u, 0u); return; }  // zero row @ n_nodes
    const float w = rsqrtf(deg[i >> 4]);   // 16 float4 per 64-float row
    const float4 f = in[i];
    union { __half2 h; unsigned u; } a, b;
    a.h = __floats2half2_rn(f.x * w, f.y * w);
    b.h = __floats2half2_rn(f.z * w, f.w * w);
    out[i] = make_uint2(a.u, b.u);
}

// ---------------- pass 2: persistent gather, 2 rows/wave, MLP=8 ------------
__global__ __launch_bounds__(256, 6) void gcn_gather8(
    const int* __restrict__ row_ptr,
    const int* __restrict__ col_idx,
    const unsigned* __restrict__ feath,   // fp16, weight-folded, 128B rows
    const float* __restrict__ deg,
    float* __restrict__ out,
    int n_nodes, int n_edges)
{
    const int lane = threadIdx.x & 63;
    const int half = lane >> 5;        // which of the 2 rows
    const int l32  = lane & 31;
    const int slot = l32 >> 3;         // edge slot 0..3 within the half
    const int k    = lane & 7;         // 16B chunk within 128B fp16 row
    const int kb   = k << 4;
    const int hb   = half << 5;
    const char* hbase = (const char*)feath;
    const int Em1  = n_edges - 1;
    const int zrow = n_nodes;

    const int wid = (blockIdx.x * blockDim.x + threadIdx.x) >> 6;
    const int nw  = (gridDim.x * blockDim.x) >> 6;
    const int npairs = (n_nodes + 1) >> 1;
    if (wid >= npairs) return;

    int pair  = wid;
    int row   = min(pair * 2 + half, n_nodes - 1);
    int start = row_ptr[row];
    int end   = row_ptr[row + 1];
    float dcur = deg[row];
    int cidx0;
    {   // preload first 32 edge indices of the first pair
        const int e = start + l32;
        cidx0 = __builtin_nontemporal_load(&col_idx[min(e, Em1)]);
        if (e >= end) cidx0 = zrow;
    }

    for (;;) {
        // ---- prefetch next pair's bounds, deg, and first col_idx block ----
        const int npair  = pair + nw;
        const int nrow   = min(min(npair, npairs - 1) * 2 + half, n_nodes - 1);
        const int nstart = row_ptr[nrow];
        const int nend   = row_ptr[nrow + 1];
        const float ndeg = deg[nrow];
        int ncidx;
        {
            const int e = nstart + l32;
            ncidx = __builtin_nontemporal_load(&col_idx[min(e, Em1)]);
            if (e >= nend) ncidx = zrow;
        }

        const int deg_r = end - start;
        const int degM  = max(deg_r, __shfl_xor(deg_r, 32));

        float acc[8] = {0.f, 0.f, 0.f, 0.f, 0.f, 0.f, 0.f, 0.f};

        int cidx = cidx0;
        int base = 0;
        for (;;) {
            // distribute 32 indices per half to 4 slots x 8 steps
            int s[8];
#pragma unroll
            for (int u = 0; u < 8; ++u) s[u] = __shfl(cidx, hb + slot + 4 * u);
            // issue ALL 8 gathers before consuming any (MLP = 8)
            v4u q[8];
#pragma unroll
            for (int u = 0; u < 8; ++u)
                q[u] = *reinterpret_cast<const v4u*>(
                    hbase + (((unsigned)s[u]) << 7) + kb);
            // unpack + accumulate (compiler drains vmcnt progressively)
#pragma unroll
            for (int u = 0; u < 8; ++u) {
#pragma unroll
                for (int p = 0; p < 4; ++p) {
                    union { unsigned uu; __half2 h; } c;
                    c.uu = q[u][p];
                    const float2 f = __half22float2(c.h);
                    acc[2 * p]     += f.x;
                    acc[2 * p + 1] += f.y;
                }
            }
            base += 32;
            if (base >= degM) break;
            // rare path (~25% of pairs): next 32-edge block
            const int e = start + base + l32;
            cidx = __builtin_nontemporal_load(&col_idx[min(e, Em1)]);
            if (e >= end) cidx = zrow;
        }

        // Reduce across the 4 slots of each half (lane bits 3,4).
#pragma unroll
        for (int m = 8; m <= 16; m <<= 1) {
#pragma unroll
            for (int i = 0; i < 8; ++i) acc[i] += __shfl_xor(acc[i], m);
        }

        if (slot == 0) {
            const float dinv = rsqrtf(dcur);   // deg clamped >= 1 by setup
            v4f lo = {acc[0] * dinv, acc[1] * dinv, acc[2] * dinv, acc[3] * dinv};
            v4f hi = {acc[4] * dinv, acc[5] * dinv, acc[6] * dinv, acc[7] * dinv};
            char* po = (char*)out + (((unsigned)row) << 8) + (k << 5);
            __builtin_nontemporal_store(lo, reinterpret_cast<v4f*>(po));
            __builtin_nontemporal_store(hi, reinterpret_cast<v4f*>(po + 16));
        }

        if (npair >= npairs) break;
        pair = npair; row = nrow; start = nstart; end = nend; dcur = ndeg;
        cidx0 = ncidx;
    }
}

// ---------------- fallback: fp32 gather (round-3 kernel) --------------------
__global__ __launch_bounds__(256) void gcn_csr_agg_f(
    const int* __restrict__ row_ptr,
    const int* __restrict__ col_idx,
    const float* __restrict__ feat,
    const float* __restrict__ deg,
    float* __restrict__ out,
    int n_nodes)
{
    const int gtid = blockIdx.x * blockDim.x + threadIdx.x;
    const int row  = gtid >> 6;
    if (row >= n_nodes) return;
    const int lane = threadIdx.x & 63;
    const int sub  = lane >> 4;
    const int fbyte = (lane & 15) << 4;

    const int start = row_ptr[row];
    const int end   = row_ptr[row + 1];
    const int last  = end - 1;
    const float dinv = rsqrtf(deg[row]);
    const char* fbase = (const char*)feat;

    v4f acc = {0.f, 0.f, 0.f, 0.f};

    for (int eb = start; eb < end; eb += 16) {
        int e[4]; int s[4]; float d[4]; v4f f[4];
#pragma unroll
        for (int u = 0; u < 4; ++u) {
            e[u] = eb + sub + 4 * u;
            const int c = min(e[u], last);
            s[u] = col_idx[c];
        }
#pragma unroll
        for (int u = 0; u < 4; ++u) {
            d[u] = deg[s[u]];
            const unsigned off = ((unsigned)s[u] << 8) + fbyte;
            f[u] = *reinterpret_cast<const v4f*>(fbase + off);
        }
#pragma unroll
        for (int u = 0; u < 4; ++u) {
            const float w = (e[u] <= last) ? dinv * rsqrtf(d[u]) : 0.f;
            acc += w * f[u];
        }
    }

    acc.x += __shfl_xor(acc.x, 16); acc.y += __shfl_xor(acc.y, 16);
    acc.z += __shfl_xor(acc.z, 16); acc.w += __shfl_xor(acc.w, 16);
    acc.x += __shfl_xor(acc.x, 32); acc.y += __shfl_xor(acc.y, 32);
    acc.z += __shfl_xor(acc.z, 32); acc.w += __shfl_xor(acc.w, 32);

    if (sub == 0) {
        v4f* po = reinterpret_cast<v4f*>((char*)out + ((unsigned)row << 8) + fbyte);
        __builtin_nontemporal_store(acc, po);
    }
}

extern "C" void kernel_launch(void* const* d_in, const int* in_sizes, int n_in,
                              void* d_out, int out_size, void* d_ws, size_t ws_size,
                              hipStream_t stream) {
    const int*   row_ptr = (const int*)d_in[0];
    const int*   col_idx = (const int*)d_in[1];
    const float* feat    = (const float*)d_in[2];
    const float* deg     = (const float*)d_in[3];
    float*       out     = (float*)d_out;

    const int n_nodes = in_sizes[0] - 1;
    const int n_edges = in_sizes[1];
    const int n_feat_elems = in_sizes[2];            // n_nodes * 64
    const size_t h_bytes = (size_t)(n_feat_elems + 64) * 2; // fp16 + zero row

    const int block = 256;

    if (ws_size >= h_bytes) {
        const int n4 = n_feat_elems >> 2;
        const int cgrid = (n4 + 16 + block - 1) / block;
        conv_fold<<<cgrid, block, 0, stream>>>(
            (const float4*)feat, deg, (uint2*)d_ws, n4);

        const int npairs = (n_nodes + 1) >> 1;
        const int max_blocks = 2048;                      // persistent grid
        long long need_blocks = ((long long)npairs * 64 + block - 1) / block;
        const int grid = (int)(need_blocks < max_blocks ? need_blocks : max_blocks);
        gcn_gather8<<<grid, block, 0, stream>>>(
            row_ptr, col_idx, (const unsigned*)d_ws, deg, out, n_nodes, n_edges);
    } else {
        const long long threads = (long long)n_nodes * 64;
        const int grid  = (int)((threads + block - 1) / block);
        gcn_csr_agg_f<<<grid, block, 0, stream>>>(
            row_ptr, col_idx, feat, deg, out, n_nodes);
    }
}

// Round 4
// 123.114 us; speedup vs baseline: 1.0433x; 1.0433x over previous
//
#include <hip/hip_runtime.h>
#include <hip/hip_fp16.h>

// GCN-style symmetric-normalized CSR aggregation.
// out[d][f] = sum_e feat[col_idx[e]][f] * rsqrt(deg[d]*deg[col_idx[e]])
//
// Round-10 theory: effective gather concurrency is ~39 lines/CU (rate x
// latency from counters), BELOW the ~64 MSHR cap -- issue-side limited.
// r9's "MLP=8" never happened: VGPR=40 proves regalloc re-serialized the
// batch. Fixes (one lever: true in-flight line count):
//  1. sched_barrier(0) between gather issue and unpack -- no early vmcnt.
//  2. launch_bounds(256,4): VGPR cap 128, q[8] (32 regs) survives regalloc.
//  3. per-lane direct col_idx loads (8-lane broadcast, L1-hot stream)
//     replace the serial 32-wide-load -> 8x ds_bpermute chain.

typedef float    v4f __attribute__((ext_vector_type(4)));
typedef unsigned v4u __attribute__((ext_vector_type(4)));

// ---------------- pass 1: fold rsqrt(deg[src]) -> fp16 table (+ zero row) ---
__global__ __launch_bounds__(256) void conv_fold(
    const float4* __restrict__ in, const float* __restrict__ deg,
    uint2* __restrict__ out, int n4)
{
    const int i = blockIdx.x * blockDim.x + threadIdx.x;
    if (i >= n4 + 16) return;
    if (i >= n4) { out[i] = make_uint2(0u, 0u); return; }  // zero row @ n_nodes
    const float w = rsqrtf(deg[i >> 4]);   // 16 float4 per 64-float row
    const float4 f = in[i];
    union { __half2 h; unsigned u; } a, b;
    a.h = __floats2half2_rn(f.x * w, f.y * w);
    b.h = __floats2half2_rn(f.z * w, f.w * w);
    out[i] = make_uint2(a.u, b.u);
}

// ---------------- pass 2: persistent gather, true 8-deep batches -----------
__global__ __launch_bounds__(256, 4) void gcn_gather_deep(
    const int* __restrict__ row_ptr,
    const int* __restrict__ col_idx,
    const unsigned* __restrict__ feath,   // fp16, weight-folded, 128B rows
    const float* __restrict__ deg,
    float* __restrict__ out,
    int n_nodes, int n_edges)
{
    const int lane = threadIdx.x & 63;
    const int half = lane >> 5;        // which of the 2 rows
    const int slot = (lane & 31) >> 3; // edge slot 0..3 within the half
    const int k    = lane & 7;         // 16B chunk within 128B fp16 row
    const int kb   = k << 4;
    const char* hbase = (const char*)feath;
    const int Em1  = n_edges - 1;
    const int zrow = n_nodes;

    const int wid = (blockIdx.x * blockDim.x + threadIdx.x) >> 6;
    const int nw  = (gridDim.x * blockDim.x) >> 6;
    const int npairs = (n_nodes + 1) >> 1;
    if (wid >= npairs) return;

    int pair  = wid;
    int row   = min(pair * 2 + half, n_nodes - 1);
    int start = row_ptr[row];
    int end   = row_ptr[row + 1];
    float dcur = deg[row];

    for (;;) {
        // ---- prefetch next pair's bounds + deg (hidden under the gather) --
        const int npair  = pair + nw;
        const int nrow   = min(min(npair, npairs - 1) * 2 + half, n_nodes - 1);
        const int nstart = row_ptr[nrow];
        const int nend   = row_ptr[nrow + 1];
        const float ndeg = deg[nrow];

        const int deg_r = end - start;
        const int degM  = max(deg_r, __shfl_xor(deg_r, 32));

        float acc[8] = {0.f, 0.f, 0.f, 0.f, 0.f, 0.f, 0.f, 0.f};

        for (int base = 0; base < degM; base += 32) {
            // per-lane col_idx: 8-lane broadcast loads, L1-hot stream.
            // lane's edge for batch u: start + base + slot + 4u (k-invariant)
            int s[8];
#pragma unroll
            for (int u = 0; u < 8; ++u) {
                const int e = start + base + slot + 4 * u;
                const int c = col_idx[min(e, Em1)];
                s[u] = (e < end) ? c : zrow;   // tail -> zero row
            }
            // issue ALL 8 gathers, then fence the scheduler so no unpack
            // (and its vmcnt wait) is hoisted into the batch.
            v4u q[8];
#pragma unroll
            for (int u = 0; u < 8; ++u)
                q[u] = *reinterpret_cast<const v4u*>(
                    hbase + (((unsigned)s[u]) << 7) + kb);
            __builtin_amdgcn_sched_barrier(0);
            // unpack + accumulate (progressive vmcnt drain in issue order)
#pragma unroll
            for (int u = 0; u < 8; ++u) {
#pragma unroll
                for (int p = 0; p < 4; ++p) {
                    union { unsigned uu; __half2 h; } c;
                    c.uu = q[u][p];
                    const float2 f = __half22float2(c.h);
                    acc[2 * p]     += f.x;
                    acc[2 * p + 1] += f.y;
                }
            }
        }

        // Reduce across the 4 slots of each half (lane bits 3,4).
#pragma unroll
        for (int m = 8; m <= 16; m <<= 1) {
#pragma unroll
            for (int i = 0; i < 8; ++i) acc[i] += __shfl_xor(acc[i], m);
        }

        if (slot == 0) {
            const float dinv = rsqrtf(dcur);   // deg clamped >= 1 by setup
            v4f lo = {acc[0] * dinv, acc[1] * dinv, acc[2] * dinv, acc[3] * dinv};
            v4f hi = {acc[4] * dinv, acc[5] * dinv, acc[6] * dinv, acc[7] * dinv};
            char* po = (char*)out + (((unsigned)row) << 8) + (k << 5);
            __builtin_nontemporal_store(lo, reinterpret_cast<v4f*>(po));
            __builtin_nontemporal_store(hi, reinterpret_cast<v4f*>(po + 16));
        }

        if (npair >= npairs) break;
        pair = npair; row = nrow; start = nstart; end = nend; dcur = ndeg;
    }
}

// ---------------- fallback: fp32 gather (round-3 kernel) --------------------
__global__ __launch_bounds__(256) void gcn_csr_agg_f(
    const int* __restrict__ row_ptr,
    const int* __restrict__ col_idx,
    const float* __restrict__ feat,
    const float* __restrict__ deg,
    float* __restrict__ out,
    int n_nodes)
{
    const int gtid = blockIdx.x * blockDim.x + threadIdx.x;
    const int row  = gtid >> 6;
    if (row >= n_nodes) return;
    const int lane = threadIdx.x & 63;
    const int sub  = lane >> 4;
    const int fbyte = (lane & 15) << 4;

    const int start = row_ptr[row];
    const int end   = row_ptr[row + 1];
    const int last  = end - 1;
    const float dinv = rsqrtf(deg[row]);
    const char* fbase = (const char*)feat;

    v4f acc = {0.f, 0.f, 0.f, 0.f};

    for (int eb = start; eb < end; eb += 16) {
        int e[4]; int s[4]; float d[4]; v4f f[4];
#pragma unroll
        for (int u = 0; u < 4; ++u) {
            e[u] = eb + sub + 4 * u;
            const int c = min(e[u], last);
            s[u] = col_idx[c];
        }
#pragma unroll
        for (int u = 0; u < 4; ++u) {
            d[u] = deg[s[u]];
            const unsigned off = ((unsigned)s[u] << 8) + fbyte;
            f[u] = *reinterpret_cast<const v4f*>(fbase + off);
        }
#pragma unroll
        for (int u = 0; u < 4; ++u) {
            const float w = (e[u] <= last) ? dinv * rsqrtf(d[u]) : 0.f;
            acc += w * f[u];
        }
    }

    acc.x += __shfl_xor(acc.x, 16); acc.y += __shfl_xor(acc.y, 16);
    acc.z += __shfl_xor(acc.z, 16); acc.w += __shfl_xor(acc.w, 16);
    acc.x += __shfl_xor(acc.x, 32); acc.y += __shfl_xor(acc.y, 32);
    acc.z += __shfl_xor(acc.z, 32); acc.w += __shfl_xor(acc.w, 32);

    if (sub == 0) {
        v4f* po = reinterpret_cast<v4f*>((char*)out + ((unsigned)row << 8) + fbyte);
        __builtin_nontemporal_store(acc, po);
    }
}

extern "C" void kernel_launch(void* const* d_in, const int* in_sizes, int n_in,
                              void* d_out, int out_size, void* d_ws, size_t ws_size,
                              hipStream_t stream) {
    const int*   row_ptr = (const int*)d_in[0];
    const int*   col_idx = (const int*)d_in[1];
    const float* feat    = (const float*)d_in[2];
    const float* deg     = (const float*)d_in[3];
    float*       out     = (float*)d_out;

    const int n_nodes = in_sizes[0] - 1;
    const int n_edges = in_sizes[1];
    const int n_feat_elems = in_sizes[2];            // n_nodes * 64
    const size_t h_bytes = (size_t)(n_feat_elems + 64) * 2; // fp16 + zero row

    const int block = 256;

    if (ws_size >= h_bytes) {
        const int n4 = n_feat_elems >> 2;
        const int cgrid = (n4 + 16 + block - 1) / block;
        conv_fold<<<cgrid, block, 0, stream>>>(
            (const float4*)feat, deg, (uint2*)d_ws, n4);

        const int npairs = (n_nodes + 1) >> 1;
        const int max_blocks = 2048;                      // persistent grid
        long long need_blocks = ((long long)npairs * 64 + block - 1) / block;
        const int grid = (int)(need_blocks < max_blocks ? need_blocks : max_blocks);
        gcn_gather_deep<<<grid, block, 0, stream>>>(
            row_ptr, col_idx, (const unsigned*)d_ws, deg, out, n_nodes, n_edges);
    } else {
        const long long threads = (long long)n_nodes * 64;
        const int grid  = (int)((threads + block - 1) / block);
        gcn_csr_agg_f<<<grid, block, 0, stream>>>(
            row_ptr, col_idx, feat, deg, out, n_nodes);
    }
}